// Round 2
// baseline (1256.726 us; speedup 1.0000x reference)
//
#include <hip/hip_runtime.h>

#define REG_CONST 0.05f
#define NCLASS 10
#define DIM 128
#define TILE 32
#define NBLOCKS 768
#define NTHREADS 256

// async global->LDS, 16B per lane. LDS dest is wave-uniform base + lane*16.
__device__ __forceinline__ void async_ld16(const void* g, void* l) {
  __builtin_amdgcn_global_load_lds(
      (const __attribute__((address_space(1))) void*)g,
      (__attribute__((address_space(3))) void*)l, 16, 0, 0);
}

__global__ __launch_bounds__(NTHREADS, 3)
void svm_fused(const float* __restrict__ X, const int* __restrict__ y,
               const float* __restrict__ w, float* __restrict__ out,
               int ntiles, float inv_n) {
  // 32 rows x 32 float4 per buffer, natural layout slot = row*32 + d4.
  // Phase-1 reads (8 rows x 8 octet-cols) and phase-2 reads (2 rows x 32 cols)
  // both land 8 distinct slots per 4-bank group -> conflict-free.
  __shared__ float4 xs[2][1024];   // 2 x 16 KiB, double-buffered X tile
  __shared__ float4 coefs[96];     // 32 rows x 3 float4 (10 coef + 2 pad)
  __shared__ float  lred[4];

  const int t    = threadIdx.x;
  const int l    = t & 63;
  const int wv   = t >> 6;
  const int dq   = l & 7;              // octet lane (phase 1)
  const int orow = wv * 8 + (l >> 3);  // phase-1 row within tile (wave-local)
  const int d4p  = l & 31;             // phase-2 column group
  const int h    = l >> 5;             // phase-2 half

  // w fragment in registers: wreg[c][j] = w4[c*32 + dq + 8*j]  (40 VGPRs)
  const float4* w4p = (const float4*)w;
  float4 wreg[10][4];
  #pragma unroll
  for (int c = 0; c < 10; ++c)
    #pragma unroll
    for (int j = 0; j < 4; ++j)
      wreg[c][j] = w4p[c * 32 + dq + 8 * j];

  const float4* X4 = (const float4*)X;

  float4 g[10];
  #pragma unroll
  for (int c = 0; c < 10; ++c) g[c] = make_float4(0.f, 0.f, 0.f, 0.f);
  float loss_acc = 0.f;

  // stage tile tix into buffer b: 4 async 1KiB copies per wave
  auto stage = [&](int tix, int b) {
    const size_t r0 = (size_t)tix * TILE;
    #pragma unroll
    for (int ii = 0; ii < 4; ++ii) {
      int row = wv * 8 + ii * 2 + (l >> 5);
      async_ld16(X4 + (r0 + row) * 32 + (l & 31),
                 &xs[b][wv * 256 + ii * 64 + l]);   // slot = row*32 + (l&31)
    }
  };

  stage(blockIdx.x, 0);                // prologue prefetch

  int it = 0;
  for (int tix = blockIdx.x; tix < ntiles; tix += gridDim.x, ++it) {
    const int cur = it & 1;
    __syncthreads();                   // drains prefetch of cur; frees cur^1
    const int nxt = tix + gridDim.x;
    if (nxt < ntiles) stage(nxt, cur ^ 1);  // overlaps with compute below
    const float4* xb = xs[cur];

    // ---- phase 1: scores (octet of lanes per row, 16 cols each) ----
    float s[10];
    #pragma unroll
    for (int c = 0; c < 10; ++c) s[c] = 0.f;
    #pragma unroll
    for (int j = 0; j < 4; ++j) {
      float4 x4 = xb[orow * 32 + dq + 8 * j];
      #pragma unroll
      for (int c = 0; c < 10; ++c) {
        float4 w4 = wreg[c][j];
        s[c] = fmaf(x4.x, w4.x, fmaf(x4.y, w4.y,
               fmaf(x4.z, w4.z, fmaf(x4.w, w4.w, s[c]))));
      }
    }
    #pragma unroll
    for (int c = 0; c < 10; ++c) {     // octet butterfly: full dot in all 8 lanes
      s[c] += __shfl_xor(s[c], 1);
      s[c] += __shfl_xor(s[c], 2);
      s[c] += __shfl_xor(s[c], 4);
    }

    int yv = y[tix * TILE + orow];
    float sy = s[0];
    #pragma unroll
    for (int c = 1; c < 10; ++c) sy = (c == yv) ? s[c] : sy;

    float cnt = 0.f, rl = 0.f;
    float cf[10];
    #pragma unroll
    for (int c = 0; c < 10; ++c) {
      float m = s[c] - sy + 1.0f;
      bool act = (m > 0.f) && (c != yv);
      cf[c] = act ? -1.f : 0.f;
      cnt += act ? 1.f : 0.f;
      rl  += act ? m : 0.f;
    }
    #pragma unroll
    for (int c = 0; c < 10; ++c) cf[c] = (c == yv) ? cnt : cf[c];

    if (dq == 0) {                     // one writer per row; rows are wave-local
      coefs[orow * 3 + 0] = make_float4(cf[0], cf[1], cf[2], cf[3]);
      coefs[orow * 3 + 1] = make_float4(cf[4], cf[5], cf[6], cf[7]);
      coefs[orow * 3 + 2] = make_float4(cf[8], cf[9], 0.f, 0.f);
      loss_acc += rl;
    }
    // no barrier: phase 2 consumes only this wave's rows (lgkmcnt ordering)

    // ---- phase 2: grad outer-product (wave-local 8 rows, 4 per half) ----
    #pragma unroll
    for (int k = 0; k < 4; ++k) {
      int r = wv * 8 + h * 4 + k;
      float4 x4 = xb[r * 32 + d4p];
      float4 c0 = coefs[r * 3 + 0];
      float4 c1 = coefs[r * 3 + 1];
      float4 c2 = coefs[r * 3 + 2];
#define ACC4(cc, gi)                         \
      g[gi].x = fmaf(cc, x4.x, g[gi].x);     \
      g[gi].y = fmaf(cc, x4.y, g[gi].y);     \
      g[gi].z = fmaf(cc, x4.z, g[gi].z);     \
      g[gi].w = fmaf(cc, x4.w, g[gi].w);
      ACC4(c0.x, 0) ACC4(c0.y, 1) ACC4(c0.z, 2) ACC4(c0.w, 3)
      ACC4(c1.x, 4) ACC4(c1.y, 5) ACC4(c1.z, 6) ACC4(c1.w, 7)
      ACC4(c2.x, 8) ACC4(c2.y, 9)
#undef ACC4
    }
  }

  // ---- loss reduction ----
  float contrib = loss_acc * inv_n;
  if (blockIdx.x == 0) {               // block 0 adds the reg terms
    float rw = 0.f;
    for (int i = t; i < NCLASS * DIM; i += NTHREADS) rw = fmaf(w[i], w[i], rw);
    contrib = fmaf(0.5f * REG_CONST, rw, contrib);
  }
  #pragma unroll
  for (int off = 32; off; off >>= 1) contrib += __shfl_down(contrib, off);
  if (l == 0) lred[wv] = contrib;
  __syncthreads();                     // also guards xs reuse below
  if (t == 0) atomicAdd(out + NCLASS * DIM, lred[0] + lred[1] + lred[2] + lred[3]);

  // ---- grad reduction: 8-way over (wave,half) groups, then atomics ----
  float4* red = &xs[0][0];             // 2048 float4 of scratch
  #pragma unroll
  for (int chunk = 0; chunk < 2; ++chunk) {
    __syncthreads();
    #pragma unroll
    for (int k = 0; k < 5; ++k) red[k * 256 + t] = g[chunk * 5 + k];
    __syncthreads();
    if (t < 160) {
      int k = t >> 5, dd = t & 31;
      float sx = 0.f, syy = 0.f, sz = 0.f, sw = 0.f;
      #pragma unroll
      for (int r8 = 0; r8 < 8; ++r8) {
        float4 v = red[k * 256 + (r8 << 5) + dd];
        sx += v.x; syy += v.y; sz += v.z; sw += v.w;
      }
      int c = chunk * 5 + k;
      int base = c * DIM + (dd << 2);
      float ax = sx * inv_n, ay = syy * inv_n, az = sz * inv_n, aw = sw * inv_n;
      if (blockIdx.x == 0) {
        ax += REG_CONST * w[base + 0];
        ay += REG_CONST * w[base + 1];
        az += REG_CONST * w[base + 2];
        aw += REG_CONST * w[base + 3];
      }
      atomicAdd(out + base + 0, ax);
      atomicAdd(out + base + 1, ay);
      atomicAdd(out + base + 2, az);
      atomicAdd(out + base + 3, aw);
    }
  }
}

extern "C" void kernel_launch(void* const* d_in, const int* in_sizes, int n_in,
                              void* d_out, int out_size, void* d_ws, size_t ws_size,
                              hipStream_t stream) {
  const float* X = (const float*)d_in[0];
  const int*   y = (const int*)d_in[1];
  const float* w = (const float*)d_in[2];
  float* out = (float*)d_out;
  int N = in_sizes[1];                 // y element count = 1,000,000
  int ntiles = N / TILE;               // 31250 (N divisible by 32)
  float inv_n = 1.0f / (float)N;
  hipMemsetAsync(d_out, 0, (size_t)out_size * sizeof(float), stream);
  svm_fused<<<NBLOCKS, NTHREADS, 0, stream>>>(X, y, w, out, ntiles, inv_n);
}

// Round 3
// 739.861 us; speedup vs baseline: 1.6986x; 1.6986x over previous
//
#include <hip/hip_runtime.h>

#define REG_CONST 0.05f
#define NCLASS 10
#define DIM 128
#define TILE 32
#define NBLOCKS 768
#define NTHREADS 256

// async global->LDS, 16B per lane. LDS dest is wave-uniform base + lane*16.
__device__ __forceinline__ void async_ld16(const void* g, void* l) {
  __builtin_amdgcn_global_load_lds(
      (const __attribute__((address_space(1))) void*)g,
      (__attribute__((address_space(3))) void*)l, 16, 0, 0);
}

__global__ __launch_bounds__(NTHREADS, 3)
void svm_fused(const float* __restrict__ X, const int* __restrict__ y,
               const float* __restrict__ w, float* __restrict__ out,
               int ntiles, float inv_n) {
  // X tile: 32 rows x 32 float4, natural layout slot = row*32 + d4.
  // Phase-1 reads (8 rows x lane-octet cols dq+8j): 64 distinct slots, 8 per
  // 4-bank group -> conflict-free. Phase-2 (2 rows x 32 cols): same. w reads:
  // 8 distinct addrs (one per group), broadcast 8 lanes each -> free.
  __shared__ float4 xs[2][1024];   // 2 x 16 KiB double-buffered X tile
  __shared__ float4 wlds[320];     // wlds[(c*4+j)*8 + dq] = w4[c*32 + dq + 8*j]
  __shared__ float4 coefs[96];     // 32 rows x 3 float4 (10 coef + 2 pad)
  __shared__ float  lred[4];

  const int t    = threadIdx.x;
  const int l    = t & 63;
  const int wv   = t >> 6;
  const int dq   = l & 7;              // octet lane (phase 1): cols {dq+8j}
  const int orow = wv * 8 + (l >> 3);  // phase-1 row (wave-local)
  const int d4p  = l & 31;             // phase-2 column group
  const int h    = l >> 5;             // phase-2 half

  const float4* w4p = (const float4*)w;
  const float4* X4  = (const float4*)X;

  // stage w into LDS (once): i = (c*4+j)*8 + dq
  for (int i = t; i < NCLASS * 4 * 8; i += NTHREADS) {
    int idq = i & 7, cj = i >> 3;
    int c = cj >> 2, j = cj & 3;
    wlds[i] = w4p[c * 32 + (j << 3) + idq];
  }

  float4 g[10];
  #pragma unroll
  for (int c = 0; c < 10; ++c) g[c] = make_float4(0.f, 0.f, 0.f, 0.f);
  float loss_acc = 0.f;

  // stage X tile tix into buffer b: 4 async 1KiB copies per wave
  auto stage = [&](int tix, int b) {
    const size_t r0 = (size_t)tix * TILE;
    #pragma unroll
    for (int ii = 0; ii < 4; ++ii) {
      int row = wv * 8 + ii * 2 + (l >> 5);
      async_ld16(X4 + (r0 + row) * 32 + (l & 31),
                 &xs[b][wv * 256 + ii * 64 + l]);   // slot = row*32 + (l&31)
    }
  };

  stage(blockIdx.x, 0);                // prologue prefetch

  int it = 0;
  for (int tix = blockIdx.x; tix < ntiles; tix += gridDim.x, ++it) {
    const int cur = it & 1;
    __syncthreads();                   // drains prefetch of cur; frees cur^1; w/coefs visible
    const int nxt = tix + gridDim.x;
    if (nxt < ntiles) stage(nxt, cur ^ 1);  // overlaps with compute below
    const float4* xb = xs[cur];
    int yv = y[tix * TILE + orow];     // independent of LDS; hides under phase 1

    // ---- phase 1: scores (octet of lanes per row, 16 cols each) ----
    float s[10];
    #pragma unroll
    for (int c = 0; c < 10; ++c) s[c] = 0.f;
    #pragma unroll
    for (int j = 0; j < 4; ++j) {
      float4 x4 = xb[orow * 32 + dq + (j << 3)];
      #pragma unroll
      for (int c = 0; c < 10; ++c) {
        float4 w4 = wlds[((c << 2) | j) * 8 + dq];
        s[c] = fmaf(x4.x, w4.x, fmaf(x4.y, w4.y,
               fmaf(x4.z, w4.z, fmaf(x4.w, w4.w, s[c]))));
      }
    }
    #pragma unroll
    for (int c = 0; c < 10; ++c) {     // octet butterfly: full dot in all 8 lanes
      s[c] += __shfl_xor(s[c], 1);
      s[c] += __shfl_xor(s[c], 2);
      s[c] += __shfl_xor(s[c], 4);
    }

    float sy = s[0];
    #pragma unroll
    for (int c = 1; c < 10; ++c) sy = (c == yv) ? s[c] : sy;

    float cnt = 0.f, rl = 0.f;
    float cf[10];
    #pragma unroll
    for (int c = 0; c < 10; ++c) {
      float m = s[c] - sy + 1.0f;
      bool act = (m > 0.f) && (c != yv);
      cf[c] = act ? -1.f : 0.f;
      cnt += act ? 1.f : 0.f;
      rl  += act ? m : 0.f;
    }
    #pragma unroll
    for (int c = 0; c < 10; ++c) cf[c] = (c == yv) ? cnt : cf[c];

    if (dq == 0) {                     // one writer per row; rows are wave-local
      coefs[orow * 3 + 0] = make_float4(cf[0], cf[1], cf[2], cf[3]);
      coefs[orow * 3 + 1] = make_float4(cf[4], cf[5], cf[6], cf[7]);
      coefs[orow * 3 + 2] = make_float4(cf[8], cf[9], 0.f, 0.f);
      loss_acc += rl;
    }
    // no barrier: phase 2 consumes only this wave's rows (in-wave lgkm order)

    // ---- phase 2: grad outer-product (wave-local 8 rows, 4 per half) ----
    #pragma unroll
    for (int k = 0; k < 4; ++k) {
      int r = wv * 8 + h * 4 + k;
      float4 x4 = xb[r * 32 + d4p];
      float4 c0 = coefs[r * 3 + 0];
      float4 c1 = coefs[r * 3 + 1];
      float4 c2 = coefs[r * 3 + 2];
#define ACC4(cc, gi)                         \
      g[gi].x = fmaf(cc, x4.x, g[gi].x);     \
      g[gi].y = fmaf(cc, x4.y, g[gi].y);     \
      g[gi].z = fmaf(cc, x4.z, g[gi].z);     \
      g[gi].w = fmaf(cc, x4.w, g[gi].w);
      ACC4(c0.x, 0) ACC4(c0.y, 1) ACC4(c0.z, 2) ACC4(c0.w, 3)
      ACC4(c1.x, 4) ACC4(c1.y, 5) ACC4(c1.z, 6) ACC4(c1.w, 7)
      ACC4(c2.x, 8) ACC4(c2.y, 9)
#undef ACC4
    }
  }

  // ---- loss reduction ----
  float contrib = loss_acc * inv_n;
  if (blockIdx.x == 0) {               // block 0 adds the reg terms
    float rw = 0.f;
    for (int i = t; i < NCLASS * DIM; i += NTHREADS) rw = fmaf(w[i], w[i], rw);
    contrib = fmaf(0.5f * REG_CONST, rw, contrib);
  }
  #pragma unroll
  for (int off = 32; off; off >>= 1) contrib += __shfl_down(contrib, off);
  if (l == 0) lred[wv] = contrib;
  __syncthreads();                     // also guards xs reuse below
  if (t == 0) atomicAdd(out + NCLASS * DIM, lred[0] + lred[1] + lred[2] + lred[3]);

  // ---- grad reduction: 8-way over (wave,half) groups, then atomics ----
  float4* red = &xs[0][0];             // 2048 float4 of scratch
  #pragma unroll
  for (int chunk = 0; chunk < 2; ++chunk) {
    __syncthreads();
    #pragma unroll
    for (int k = 0; k < 5; ++k) red[k * 256 + t] = g[chunk * 5 + k];
    __syncthreads();
    if (t < 160) {
      int k = t >> 5, dd = t & 31;
      float sx = 0.f, syy = 0.f, sz = 0.f, sw = 0.f;
      #pragma unroll
      for (int r8 = 0; r8 < 8; ++r8) {
        float4 v = red[k * 256 + (r8 << 5) + dd];
        sx += v.x; syy += v.y; sz += v.z; sw += v.w;
      }
      int c = chunk * 5 + k;
      int base = c * DIM + (dd << 2);
      float ax = sx * inv_n, ay = syy * inv_n, az = sz * inv_n, aw = sw * inv_n;
      if (blockIdx.x == 0) {
        ax += REG_CONST * w[base + 0];
        ay += REG_CONST * w[base + 1];
        az += REG_CONST * w[base + 2];
        aw += REG_CONST * w[base + 3];
      }
      atomicAdd(out + base + 0, ax);
      atomicAdd(out + base + 1, ay);
      atomicAdd(out + base + 2, az);
      atomicAdd(out + base + 3, aw);
    }
  }
}

extern "C" void kernel_launch(void* const* d_in, const int* in_sizes, int n_in,
                              void* d_out, int out_size, void* d_ws, size_t ws_size,
                              hipStream_t stream) {
  const float* X = (const float*)d_in[0];
  const int*   y = (const int*)d_in[1];
  const float* w = (const float*)d_in[2];
  float* out = (float*)d_out;
  int N = in_sizes[1];                 // y element count = 1,000,000
  int ntiles = N / TILE;               // 31250 (N divisible by 32)
  float inv_n = 1.0f / (float)N;
  hipMemsetAsync(d_out, 0, (size_t)out_size * sizeof(float), stream);
  svm_fused<<<NBLOCKS, NTHREADS, 0, stream>>>(X, y, w, out, ntiles, inv_n);
}